// Round 5
// baseline (484.157 us; speedup 1.0000x reference)
//
#include <hip/hip_runtime.h>

#define COST_CLASS 1.0f
#define COST_BBOX  5.0f
#define COST_GIOU  2.0f
#define EPS 1e-6f

// Problem constants (from setup_inputs): B=32, Q=300, C=11, T=3200
constexpr int kC  = 11;
constexpr int TPB = 256;   // threads per block, each thread owns 4 consecutive targets
constexpr int NPT = 4;     // R4: 8->4, shrink live state -> target 5 waves/SIMD

typedef float vf4 __attribute__((ext_vector_type(4)));

__device__ __forceinline__ float fast_rcp(float x) {
    return __builtin_amdgcn_rcpf(x);   // v_rcp_f32, ~1 ulp — fine vs 0.4 absmax threshold
}

// ---------------- Kernel A: softmax -> TRANSPOSED, pre-folded class cost ----
// probsT[c][n] = 2 - softmax(logits[n])[c]; the 2 folds the GIoU identity
//   (carea-uni)/(carea+EPS) == 1 - (uni+EPS)/(carea+EPS).
__global__ void softmax_probsT_kernel(const float* __restrict__ logits,
                                      float* __restrict__ probsT, int N) {
    int n = blockIdx.x * blockDim.x + threadIdx.x;
    if (n >= N) return;
    float v[kC];
    float m = -1e30f;
#pragma unroll
    for (int c = 0; c < kC; ++c) {
        v[c] = logits[n * kC + c];
        m = fmaxf(m, v[c]);
    }
    float s = 0.f;
#pragma unroll
    for (int c = 0; c < kC; ++c) {
        v[c] = __expf(v[c] - m);
        s += v[c];
    }
    float inv = fast_rcp(s);
#pragma unroll
    for (int c = 0; c < kC; ++c)
        probsT[(size_t)c * N + n] = fmaf(-v[c], inv, 2.0f);   // 2 - prob
}

// ---------------- shared cost-matrix body ----------------
// REPEAT>1 (diagnostic only): per-pass CSE perturbation + row rotation so no
// pass is dead; per-pass cost = dispatch_dur / REPEAT.
template<int REPEAT>
__device__ __forceinline__ void cost_impl(const float* __restrict__ probsT,
                                          const float* __restrict__ pred_boxes,
                                          const int*   __restrict__ labels,
                                          const float* __restrict__ tboxes,
                                          float* __restrict__ out,
                                          int N, int T) {
    int n0 = blockIdx.y * NPT;
    int t4 = blockIdx.x * TPB + threadIdx.x;   // group of 4 targets
    if (t4 >= (T >> 2)) return;
    int tbase = t4 << 2;

    // class-cost vectors: ccv[j][i] = probsT[lab[j]][n0+i], one 16B load each
    int4 labv = ((const int4*)labels)[t4];
    const int labs[4] = {labv.x, labv.y, labv.z, labv.w};
    vf4 ccv[4];
#pragma unroll
    for (int j = 0; j < 4; ++j)
        ccv[j] = *(const vf4*)(probsT + (size_t)labs[j] * N + n0);

    // 4 targets in registers (reused across NPT preds)
    float4 tb[4];
    float tx0[4], ty0[4], tx1[4], ty1[4], tarea[4];
#pragma unroll
    for (int j = 0; j < 4; ++j) {
        tb[j] = ((const float4*)tboxes)[tbase + j];
        tx0[j] = tb[j].x - 0.5f * tb[j].z;
        ty0[j] = tb[j].y - 0.5f * tb[j].w;
        tx1[j] = tb[j].x + 0.5f * tb[j].z;
        ty1[j] = tb[j].y + 0.5f * tb[j].w;
        tarea[j] = (tx1[j] - tx0[j]) * (ty1[j] - ty0[j]);
    }

#pragma unroll 1
    for (int r = 0; r < REPEAT; ++r) {
#pragma unroll
        for (int i = 0; i < NPT; ++i) {
            int n = n0 + i;
            float4 pb = ((const float4*)pred_boxes)[n];  // block-uniform -> s_load
            if constexpr (REPEAT > 1)
                pb.x += (float)r * 1e-20f;               // per-pass CSE breaker

            float p_x0 = pb.x - 0.5f * pb.z;
            float p_y0 = pb.y - 0.5f * pb.w;
            float p_x1 = pb.x + 0.5f * pb.z;
            float p_y1 = pb.y + 0.5f * pb.w;
            float p_area = (p_x1 - p_x0) * (p_y1 - p_y0);

            vf4 res;
#pragma unroll
            for (int j = 0; j < 4; ++j) {
                // L1 on cxcywh (abs folds into VOP3 input modifiers)
                float cb = fabsf(pb.x - tb[j].x) + fabsf(pb.y - tb[j].y) +
                           fabsf(pb.z - tb[j].z) + fabsf(pb.w - tb[j].w);
                // GIoU pieces — divisions via v_rcp_f32
                float lt_x = fmaxf(p_x0, tx0[j]), lt_y = fmaxf(p_y0, ty0[j]);
                float rb_x = fminf(p_x1, tx1[j]), rb_y = fminf(p_y1, ty1[j]);
                float iw = fmaxf(rb_x - lt_x, 0.f), ih = fmaxf(rb_y - lt_y, 0.f);
                float inter = iw * ih;
                float u = p_area + tarea[j] - inter + EPS;   // union + EPS
                float iou = inter * fast_rcp(u);
                float cx0 = fminf(p_x0, tx0[j]), cy0 = fminf(p_y0, ty0[j]);
                float cx1 = fmaxf(p_x1, tx1[j]), cy1 = fmaxf(p_y1, ty1[j]);
                // boxes have w,h >= 0 -> enclosure extents provably >= 0
                float carea = (cx1 - cx0) * (cy1 - cy0);
                float g = u * fast_rcp(carea + EPS);         // (uni+EPS)/(carea+EPS)
                // cost = (2-prob) + 5*cb - 2*iou - 2*g  (2 pre-folded in probsT)
                float rr = fmaf(COST_BBOX, cb, ccv[j][i]);
                rr = fmaf(-2.0f, iou, rr);
                res[j] = fmaf(-2.0f, g, rr);
            }

            int nn = n;
            if constexpr (REPEAT > 1) {
                nn += r * NPT;               // rotate rows per pass: defeats DSE,
                if (nn >= N) nn -= N;        // same footprint & coalescing
            }
            *(vf4*)(out + (size_t)nn * T + tbase) = res;
        }
    }
}

// Production and diagnostic are SEPARATE kernels (independent regalloc, so the
// diag row's VGPR_Count/VALUBusy speak for the production configuration
// without template cross-contamination).
__global__ __launch_bounds__(TPB, 5)
void cost_matrix_kernel(const float* __restrict__ probsT,
                        const float* __restrict__ pred_boxes,
                        const int*   __restrict__ labels,
                        const float* __restrict__ tboxes,
                        float* __restrict__ out, int N, int T) {
    cost_impl<1>(probsT, pred_boxes, labels, tboxes, out, N, T);
}

__global__ __launch_bounds__(TPB, 5)
void cost_matrix_diag(const float* __restrict__ probsT,
                      const float* __restrict__ pred_boxes,
                      const int*   __restrict__ labels,
                      const float* __restrict__ tboxes,
                      float* __restrict__ out, int N, int T) {
    cost_impl<2>(probsT, pred_boxes, labels, tboxes, out, N, T);
}

extern "C" void kernel_launch(void* const* d_in, const int* in_sizes, int n_in,
                              void* d_out, int out_size, void* d_ws, size_t ws_size,
                              hipStream_t stream) {
    const float* class_logits  = (const float*)d_in[0];  // [B,Q,C]
    const float* bbox_coords   = (const float*)d_in[1];  // [B,Q,4]
    const int*   target_labels = (const int*)d_in[2];    // [T]
    const float* target_boxes  = (const float*)d_in[3];  // [T,4]
    float* out = (float*)d_out;

    int N = in_sizes[0] / kC;  // 9600
    int T = in_sizes[2];       // 3200

    float* probsT = (float*)d_ws;                                    // 422 KB
    float* vout   = (float*)((char*)d_ws + (size_t)16 * 1024 * 1024); // 122.9 MB

    {
        int tpb = 256;
        int blocks = (N + tpb - 1) / tpb;
        softmax_probsT_kernel<<<blocks, tpb, 0, stream>>>(class_logits, probsT, N);
    }

    dim3 grid((T / 4 + TPB - 1) / TPB, N / NPT);

    // Diagnostic: same body, REPEAT=2, workspace only. Dispatch dur ~ 2x the
    // production kernel -> guaranteed to beat the ~73us fills into rocprof
    // top-5, finally yielding VGPR/VALUBusy/WRITE_SIZE for this exact config.
    if (ws_size >= (size_t)160 * 1024 * 1024) {
        cost_matrix_diag<<<grid, TPB, 0, stream>>>(probsT, bbox_coords,
            target_labels, target_boxes, vout, N, T);
    }

    // Kernel of record.
    cost_matrix_kernel<<<grid, TPB, 0, stream>>>(probsT, bbox_coords,
        target_labels, target_boxes, out, N, T);
}

// Round 6
// 151.183 us; speedup vs baseline: 3.2025x; 3.2025x over previous
//
#include <hip/hip_runtime.h>

#define COST_CLASS 1.0f
#define COST_BBOX  5.0f
#define COST_GIOU  2.0f
#define EPS 1e-6f

// Problem constants (from setup_inputs): B=32, Q=300, C=11, T=3200
constexpr int kC  = 11;
constexpr int TPB = 64;    // R6: 1 wave per block -> minimal x-tail waste (800 t4 groups)
constexpr int NPT = 8;     // preds per inner chunk (proven R1 inner structure)
constexpr int RB  = 4;     // R6: row-blocks per thread -> 32 preds/thread, 4x fewer waves

typedef float vf4 __attribute__((ext_vector_type(4)));
typedef float vf8 __attribute__((ext_vector_type(8)));

__device__ __forceinline__ float fast_rcp(float x) {
    return __builtin_amdgcn_rcpf(x);   // v_rcp_f32, ~1 ulp — fine vs 0.4 absmax threshold
}

// ---------------- Kernel A: softmax -> TRANSPOSED, pre-folded class cost ----
// probsT[c][n] = 2 - softmax(logits[n])[c]; the 2 folds the GIoU identity
//   (carea-uni)/(carea+EPS) == 1 - (uni+EPS)/(carea+EPS).
__global__ void softmax_probsT_kernel(const float* __restrict__ logits,
                                      float* __restrict__ probsT, int N) {
    int n = blockIdx.x * blockDim.x + threadIdx.x;
    if (n >= N) return;
    float v[kC];
    float m = -1e30f;
#pragma unroll
    for (int c = 0; c < kC; ++c) {
        v[c] = logits[n * kC + c];
        m = fmaxf(m, v[c]);
    }
    float s = 0.f;
#pragma unroll
    for (int c = 0; c < kC; ++c) {
        v[c] = __expf(v[c] - m);
        s += v[c];
    }
    float inv = fast_rcp(s);
#pragma unroll
    for (int c = 0; c < kC; ++c)
        probsT[(size_t)c * N + n] = fmaf(-v[c], inv, 2.0f);   // 2 - prob
}

// ---------------- Kernel B: cost matrix, long-lived waves ----------------
// R6 theory: the ~70us plateau is short-wave overhead (prologue + un-hidden
// latency + serial store drain), not any single pipe. Each thread now keeps
// its 4-target state and loops RB=4 row-blocks of NPT=8 preds: 4x fewer
// waves, prologue amortized 4x, 32 stores interleaved with compute.
// NO __launch_bounds__ min-waves clamp: R5 measured that (TPB,5) squeezed
// VGPR to 48 and spilled ~1GB of scratch traffic (VALUBusy 14%). Let the
// allocator land naturally (~100-120 VGPR -> 4 waves/SIMD).
__global__ void cost_matrix_kernel(const float* __restrict__ probsT,      // [C,N] (=2-prob)
                                   const float* __restrict__ pred_boxes,  // [N,4] cxcywh
                                   const int*   __restrict__ labels,      // [T]
                                   const float* __restrict__ tboxes,      // [T,4] cxcywh
                                   float* __restrict__ out,               // [N,T]
                                   int N, int T) {
    int t4 = blockIdx.x * TPB + threadIdx.x;   // group of 4 targets
    if (t4 >= (T >> 2)) return;
    int tbase = t4 << 2;

    // --- 4 targets in registers (reused across RB*NPT = 32 preds) ---
    int4 labv = ((const int4*)labels)[t4];
    const int labs[4] = {labv.x, labv.y, labv.z, labv.w};
    float4 tb[4];
    float tx0[4], ty0[4], tx1[4], ty1[4], tarea[4];
#pragma unroll
    for (int j = 0; j < 4; ++j) {
        tb[j] = ((const float4*)tboxes)[tbase + j];
        tx0[j] = tb[j].x - 0.5f * tb[j].z;
        ty0[j] = tb[j].y - 0.5f * tb[j].w;
        tx1[j] = tb[j].x + 0.5f * tb[j].z;
        ty1[j] = tb[j].y + 0.5f * tb[j].w;
        tarea[j] = (tx1[j] - tx0[j]) * (ty1[j] - ty0[j]);
    }

#pragma unroll 1
    for (int rb = 0; rb < RB; ++rb) {
        int n0 = blockIdx.y * (NPT * RB) + rb * NPT;

        // class-cost vectors for this row-block: one 32B load per target
        // (probsT is 422 KB -> L1/L2-hot; offsets 32B-aligned)
        vf8 ccv[4];
#pragma unroll
        for (int j = 0; j < 4; ++j)
            ccv[j] = *(const vf8*)(probsT + (size_t)labs[j] * N + n0);

#pragma unroll
        for (int i = 0; i < NPT; ++i) {
            int n = n0 + i;
            float4 pb = ((const float4*)pred_boxes)[n];  // block-uniform -> s_load
            float p_x0 = pb.x - 0.5f * pb.z;
            float p_y0 = pb.y - 0.5f * pb.w;
            float p_x1 = pb.x + 0.5f * pb.z;
            float p_y1 = pb.y + 0.5f * pb.w;
            float p_area = (p_x1 - p_x0) * (p_y1 - p_y0);

            vf4 res;
#pragma unroll
            for (int j = 0; j < 4; ++j) {
                // L1 on cxcywh (abs folds into VOP3 input modifiers)
                float cb = fabsf(pb.x - tb[j].x) + fabsf(pb.y - tb[j].y) +
                           fabsf(pb.z - tb[j].z) + fabsf(pb.w - tb[j].w);
                // GIoU pieces — divisions via v_rcp_f32
                float lt_x = fmaxf(p_x0, tx0[j]), lt_y = fmaxf(p_y0, ty0[j]);
                float rb_x = fminf(p_x1, tx1[j]), rb_y = fminf(p_y1, ty1[j]);
                float iw = fmaxf(rb_x - lt_x, 0.f), ih = fmaxf(rb_y - lt_y, 0.f);
                float inter = iw * ih;
                float u = p_area + tarea[j] - inter + EPS;   // union + EPS
                float iou = inter * fast_rcp(u);
                float cx0 = fminf(p_x0, tx0[j]), cy0 = fminf(p_y0, ty0[j]);
                float cx1 = fmaxf(p_x1, tx1[j]), cy1 = fmaxf(p_y1, ty1[j]);
                // boxes have w,h >= 0 -> enclosure extents provably >= 0
                float carea = (cx1 - cx0) * (cy1 - cy0);
                float g = u * fast_rcp(carea + EPS);         // (uni+EPS)/(carea+EPS)
                // cost = (2-prob) + 5*cb - 2*iou - 2*g  (2 pre-folded in probsT)
                float rr = fmaf(COST_BBOX, cb, ccv[j][i]);
                rr = fmaf(-2.0f, iou, rr);
                res[j] = fmaf(-2.0f, g, rr);
            }
            *(vf4*)(out + (size_t)n * T + tbase) = res;   // plain write-back store
        }
    }
}

extern "C" void kernel_launch(void* const* d_in, const int* in_sizes, int n_in,
                              void* d_out, int out_size, void* d_ws, size_t ws_size,
                              hipStream_t stream) {
    const float* class_logits  = (const float*)d_in[0];  // [B,Q,C]
    const float* bbox_coords   = (const float*)d_in[1];  // [B,Q,4]
    const int*   target_labels = (const int*)d_in[2];    // [T]
    const float* target_boxes  = (const float*)d_in[3];  // [T,4]
    float* out = (float*)d_out;

    int N = in_sizes[0] / kC;  // 9600
    int T = in_sizes[2];       // 3200

    float* probsT = (float*)d_ws;   // C*N floats = 422 KB, fully overwritten

    {
        int tpb = 256;
        int blocks = (N + tpb - 1) / tpb;
        softmax_probsT_kernel<<<blocks, tpb, 0, stream>>>(class_logits, probsT, N);
    }
    {
        // grid.x: 800 target-groups / 64 = 12.5 -> 13 (last wave half-active)
        // grid.y: N / 32 preds-per-thread = 300
        dim3 grid((T / 4 + TPB - 1) / TPB, N / (NPT * RB));
        cost_matrix_kernel<<<grid, TPB, 0, stream>>>(probsT, bbox_coords,
                                                     target_labels, target_boxes,
                                                     out, N, T);
    }
}